// Round 4
// baseline (529.190 us; speedup 1.0000x reference)
//
#include <hip/hip_runtime.h>
#include <hip/hip_bf16.h>

typedef __bf16 bf16;
typedef __bf16 bf16x8 __attribute__((ext_vector_type(8)));
typedef float f32x4 __attribute__((ext_vector_type(4)));

#define B_    2
#define S_    2048
#define HD    2048
#define NH    16
#define DQK   192
#define DV    128
#define QR    1536
#define KVR   512
#define NTOK  4096
#define NKVB  4096   /* N_HEADS*(D_NOPE+D_V) */
#define NQB   3072   /* N_HEADS*D_QK */

static __device__ __forceinline__ void gload16(const void* g, void* l) {
  __builtin_amdgcn_global_load_lds(
      (const __attribute__((address_space(1))) void*)g,
      (__attribute__((address_space(3))) void*)l, 16, 0, 0);
}

// ---------------- f32 -> bf16 convert ----------------
__global__ __launch_bounds__(256) void cvt_bf16(const float* __restrict__ in,
                                                bf16* __restrict__ out, long n) {
  long i = ((long)blockIdx.x * 256 + threadIdx.x) * 4;
  if (i + 3 < n) {
    float4 v = *(const float4*)(in + i);
    out[i] = (bf16)v.x; out[i+1] = (bf16)v.y; out[i+2] = (bf16)v.z; out[i+3] = (bf16)v.w;
  }
}

// ---------------- transpose f32 [R][C] -> bf16 [Np][R], zero-pad rows >= C ----
__global__ __launch_bounds__(256) void transpose_cvt(const float* __restrict__ in,
                                                     bf16* __restrict__ out,
                                                     int R, int C, int Np) {
  __shared__ float tile[32][33];
  int c0 = blockIdx.x * 32;
  int r0 = blockIdx.y * 32;
  int tx = threadIdx.x & 31, ty = threadIdx.x >> 5;
#pragma unroll
  for (int i = 0; i < 4; ++i) {
    int r = r0 + ty + i * 8, c = c0 + tx;
    tile[ty + i * 8][tx] = (c < C) ? in[(long)r * C + c] : 0.f;
  }
  __syncthreads();
#pragma unroll
  for (int i = 0; i < 4; ++i) {
    int oc = c0 + ty + i * 8;
    if (oc < Np) out[(long)oc * R + r0 + tx] = (bf16)tile[tx][ty + i * 8];
  }
}

// ---------------- GEMM: C[M][N] = A[M][K] bf16 @ Bt[N][K] bf16 ----------------
template <typename CT>
__global__ __launch_bounds__(256) void gemm_bf16(const bf16* __restrict__ A,
                                                 const bf16* __restrict__ Bt,
                                                 CT* __restrict__ C,
                                                 int M, int N, int K) {
  __shared__ bf16 As[128 * 32];
  __shared__ bf16 Bs[128 * 32];
  const int t = threadIdx.x;
  const int l = t & 63;
  const int w = t >> 6;
  const int m0 = blockIdx.y * 128;
  const int n0 = blockIdx.x * 128;
  const int wr = (w >> 1) * 64;
  const int wc = (w & 1) * 64;
  const int lr = l & 15;
  const int lg = l >> 4;

  f32x4 acc[4][4] = {};

  for (int k0 = 0; k0 < K; k0 += 32) {
    __syncthreads();
#pragma unroll
    for (int j = 0; j < 2; ++j) {
      int c = j * 256 + t;
      int row = c >> 2, kk = (c & 3) * 8;
      bf16* abase = As + (j * 256 + w * 64) * 8;
      bf16* bbase = Bs + (j * 256 + w * 64) * 8;
      gload16(A  + (long)(m0 + row) * K + k0 + kk, abase);
      gload16(Bt + (long)(n0 + row) * K + k0 + kk, bbase);
    }
    __syncthreads();
    bf16x8 af[4], bfr[4];
#pragma unroll
    for (int m = 0; m < 4; ++m)
      af[m] = *(const bf16x8*)(As + (wr + m * 16 + lr) * 32 + lg * 8);
#pragma unroll
    for (int n = 0; n < 4; ++n)
      bfr[n] = *(const bf16x8*)(Bs + (wc + n * 16 + lr) * 32 + lg * 8);
#pragma unroll
    for (int m = 0; m < 4; ++m)
#pragma unroll
      for (int n = 0; n < 4; ++n)
        acc[m][n] = __builtin_amdgcn_mfma_f32_16x16x32_bf16(af[m], bfr[n], acc[m][n], 0, 0, 0);
  }
#pragma unroll
  for (int m = 0; m < 4; ++m)
#pragma unroll
    for (int n = 0; n < 4; ++n)
#pragma unroll
      for (int v = 0; v < 4; ++v) {
        int row = m0 + wr + m * 16 + lg * 4 + v;
        int col = n0 + wc + n * 16 + lr;
        C[(long)row * N + col] = (CT)acc[m][n][v];
      }
}

// ---------------- RMSNorm (q path): [NTOK][QR] bf16 -> bf16 -------------------
__global__ __launch_bounds__(256) void rmsnorm_q(const bf16* __restrict__ in,
                                                 const float* __restrict__ g,
                                                 bf16* __restrict__ out) {
  int row = blockIdx.x;
  const bf16* x = in + (long)row * QR;
  float ss = 0.f;
  for (int j = threadIdx.x; j < QR; j += 256) { float v = (float)x[j]; ss += v * v; }
#pragma unroll
  for (int m = 1; m < 64; m <<= 1) ss += __shfl_xor(ss, m);
  __shared__ float red[4];
  if ((threadIdx.x & 63) == 0) red[threadIdx.x >> 6] = ss;
  __syncthreads();
  ss = red[0] + red[1] + red[2] + red[3];
  float rs = rsqrtf(ss / QR + 1e-5f);
  for (int j = threadIdx.x; j < QR; j += 256)
    out[(long)row * QR + j] = (bf16)((float)x[j] * rs * g[j]);
}

// ---------------- kv prep: RMSNorm latent + RoPE k_rope broadcast -------------
__global__ __launch_bounds__(256) void kv_prep(const bf16* __restrict__ kv_a,  // [NTOK][640]
                                               const float* __restrict__ g,    // [512]
                                               const int* __restrict__ pos,
                                               const float* __restrict__ cosT, // [S][32]
                                               const float* __restrict__ sinT,
                                               bf16* __restrict__ kv_l,        // [NTOK][512]
                                               bf16* __restrict__ k_bhsd) {    // [B][H][S][192]
  int row = blockIdx.x;
  int b = row / S_, s = row % S_;
  const bf16* x = kv_a + (long)row * 640;
  float ss = 0.f;
  for (int j = threadIdx.x; j < KVR; j += 256) { float v = (float)x[j]; ss += v * v; }
#pragma unroll
  for (int m = 1; m < 64; m <<= 1) ss += __shfl_xor(ss, m);
  __shared__ float red[4];
  if ((threadIdx.x & 63) == 0) red[threadIdx.x >> 6] = ss;
  __syncthreads();
  ss = red[0] + red[1] + red[2] + red[3];
  float rs = rsqrtf(ss / KVR + 1e-5f);
  for (int j = threadIdx.x; j < KVR; j += 256)
    kv_l[(long)row * KVR + j] = (bf16)((float)x[j] * rs * g[j]);
  if (threadIdx.x < 32) {
    int i = threadIdx.x;
    int p = pos[s] & (S_ - 1);
    float c = cosT[p * 32 + i], sn = sinT[p * 32 + i];
    float x0 = (float)x[512 + i], x1 = (float)x[544 + i];
    bf16 r0 = (bf16)(x0 * c - x1 * sn);
    bf16 r1 = (bf16)(x0 * sn + x1 * c);
    for (int h = 0; h < NH; ++h) {
      long base = (((long)(b * NH + h)) * S_ + s) * DQK;
      k_bhsd[base + 128 + i] = r0;
      k_bhsd[base + 160 + i] = r1;
    }
  }
}

// ---------------- q scatter: RoPE + SCALE, [NTOK][3072] bf16 -> q_bhsd bf16 ---
__global__ __launch_bounds__(256) void scatter_q(const bf16* __restrict__ q,
                                                 const int* __restrict__ pos,
                                                 const float* __restrict__ cosT,
                                                 const float* __restrict__ sinT,
                                                 bf16* __restrict__ q_bhsd) {
  const float SCALE = 0.07216878364870323f;  // 192^-0.5
  int row = blockIdx.x;
  int b = row / S_, s = row % S_;
  int p = pos[s] & (S_ - 1);
  const bf16* qr = q + (long)row * NQB;
  for (int j = threadIdx.x; j < NQB; j += 256) {
    int h = j / DQK, jj = j - h * DQK;
    float v;
    if (jj < 128) {
      v = (float)qr[j];
    } else if (jj < 160) {
      int i = jj - 128;
      v = (float)qr[h * DQK + 128 + i] * cosT[p * 32 + i] - (float)qr[h * DQK + 160 + i] * sinT[p * 32 + i];
    } else {
      int i = jj - 160;
      v = (float)qr[h * DQK + 128 + i] * sinT[p * 32 + i] + (float)qr[h * DQK + 160 + i] * cosT[p * 32 + i];
    }
    q_bhsd[(((long)(b * NH + h)) * S_ + s) * DQK + jj] = (bf16)(v * SCALE);
  }
}

// ---------------- split k_nope out of kv_b ------------------------------------
__global__ __launch_bounds__(256) void split_k(const bf16* __restrict__ kv_b,
                                               bf16* __restrict__ k_bhsd) {
  int row = blockIdx.x;
  int b = row / S_, s = row % S_;
  for (int j = threadIdx.x; j < 2048; j += 256) {
    int h = j >> 7, d = j & 127;
    k_bhsd[(((long)(b * NH + h)) * S_ + s) * DQK + d] = kv_b[(long)row * NKVB + h * 256 + d];
  }
}

// ---------------- V transpose: kv_b v-part -> v_t [BH][128][S] bf16 -----------
__global__ __launch_bounds__(256) void v_trans(const bf16* __restrict__ kv_b,
                                               bf16* __restrict__ v_t) {
  __shared__ bf16 tile[32][33];
  int st = blockIdx.x, dt = blockIdx.y, bh = blockIdx.z;
  int b = bh >> 4, h = bh & 15;
  int tx = threadIdx.x & 31, ty = threadIdx.x >> 5;
#pragma unroll
  for (int i = 0; i < 4; ++i) {
    int s = st * 32 + ty + i * 8, d = dt * 32 + tx;
    tile[ty + i * 8][tx] = kv_b[((long)(b * S_ + s)) * NKVB + h * 256 + 128 + d];
  }
  __syncthreads();
#pragma unroll
  for (int i = 0; i < 4; ++i) {
    int d = dt * 32 + ty + i * 8, s = st * 32 + tx;
    v_t[((long)bh * DV + d) * S_ + s] = tile[tx][ty + i * 8];
  }
}

// ---------------- flash v3: 4 waves x 32 q-rows, K double-buffered, V from L2 -
// QBLK=128, KVB=64. K staged via gload16 with XOR chunk swizzle into 2 LDS
// buffers; counted vmcnt(6) + raw s_barrier keeps next-tile loads in flight.
#define KVB  64
__global__ __launch_bounds__(256) void flash3(const bf16* __restrict__ q_bhsd,
                                              const bf16* __restrict__ k_bhsd,
                                              const bf16* __restrict__ v_t,
                                              bf16* __restrict__ att) {  // [NTOK][2048]
  __shared__ bf16 Ks[2][KVB * DQK];   // 2 x 24 KB, swizzled 16B chunks
  __shared__ bf16 Ps[4][32 * 72];     // 18 KB, per-wave P, padded to 72
  int bid = blockIdx.x;
  int bh = bid & 31;                  // fixes XCD; 16 q-blocks share K/V in L2
  int qt = 15 - (bid >> 5);           // heaviest first
  int b = bh >> 4, h = bh & 15;
  int q0 = qt * 128;
  int t = threadIdx.x;
  int w = t >> 6, l = t & 63;
  int lr = l & 15, lg = l >> 4;
  int qw = q0 + w * 32;               // this wave's first q row
  const int lr7 = lr & 7;

  const bf16* Qb = q_bhsd + (long)bh * S_ * DQK;
  const bf16* Kb = k_bhsd + (long)bh * S_ * DQK;
  const bf16* Vb = v_t + (long)bh * DV * S_;

  bf16x8 qf[2][6];
#pragma unroll
  for (int rg = 0; rg < 2; ++rg)
#pragma unroll
    for (int t6 = 0; t6 < 6; ++t6)
      qf[rg][t6] = *(const bf16x8*)(Qb + (long)(qw + rg * 16 + lr) * DQK + t6 * 32 + lg * 8);

  f32x4 oacc[2][8] = {};
  float mrow[2][4] = {{-1e30f,-1e30f,-1e30f,-1e30f},{-1e30f,-1e30f,-1e30f,-1e30f}};
  float lrow[2][4] = {};

  int nkt = 2 * qt + 2;

  // stage K tile kt into buffer bb (6 gload16 per thread, chunk^row swizzle)
#define STAGEK(kt, bb)                                                        \
  {                                                                           \
    _Pragma("unroll")                                                         \
    for (int j = 0; j < 6; ++j) {                                             \
      int s_ = j * 256 + t;                                                   \
      int r_ = s_ / 24, c1_ = s_ - r_ * 24;                                   \
      int c_ = c1_ ^ (r_ & 7);                                                \
      gload16(Kb + (long)((kt) * KVB + r_) * DQK + c_ * 8,                    \
              &Ks[bb][(j * 256 + w * 64) * 8]);                               \
    }                                                                         \
  }

  STAGEK(0, 0)
  for (int kt = 0; kt < nkt; ++kt) {
    int cur = kt & 1;
    int k0 = kt * KVB;
    if (kt + 1 < nkt) {
      STAGEK(kt + 1, cur ^ 1)
      asm volatile("s_waitcnt vmcnt(6)" ::: "memory");
    } else {
      asm volatile("s_waitcnt vmcnt(0)" ::: "memory");
    }
    __builtin_amdgcn_s_barrier();

    if (k0 <= qw + 31) {
      // ---- QK^T: sacc[rg][n] = scores[q=qw+rg*16+lg*4+v][k=k0+n*16+lr] ----
      f32x4 sacc[2][4] = {};
#pragma unroll
      for (int n = 0; n < 4; ++n) {
        int rk = n * 16 + lr;
#pragma unroll
        for (int t6 = 0; t6 < 6; ++t6) {
          bf16x8 kf = *(const bf16x8*)(&Ks[cur][rk * DQK + (((t6 * 4 + lg) ^ lr7) << 3)]);
          sacc[0][n] = __builtin_amdgcn_mfma_f32_16x16x32_bf16(qf[0][t6], kf, sacc[0][n], 0, 0, 0);
          sacc[1][n] = __builtin_amdgcn_mfma_f32_16x16x32_bf16(qf[1][t6], kf, sacc[1][n], 0, 0, 0);
        }
      }
      // ---- causal mask (diagonal region only) ----
      if (k0 + KVB - 1 > qw) {
#pragma unroll
        for (int rg = 0; rg < 2; ++rg)
#pragma unroll
          for (int n = 0; n < 4; ++n)
#pragma unroll
            for (int v = 0; v < 4; ++v) {
              int r = rg * 16 + lg * 4 + v, c = n * 16 + lr;
              if (k0 + c > qw + r) sacc[rg][n][v] = -1e30f;
            }
      }
      // ---- online softmax (per 16-row group) ----
#pragma unroll
      for (int rg = 0; rg < 2; ++rg) {
        float corr[4], p[4][4];
#pragma unroll
        for (int v = 0; v < 4; ++v) {
          float mv = fmaxf(fmaxf(sacc[rg][0][v], sacc[rg][1][v]),
                           fmaxf(sacc[rg][2][v], sacc[rg][3][v]));
#pragma unroll
          for (int msk = 1; msk < 16; msk <<= 1) mv = fmaxf(mv, __shfl_xor(mv, msk));
          float mt = fmaxf(mrow[rg][v], mv);
          corr[v] = __expf(mrow[rg][v] - mt);
          float ps = 0.f;
#pragma unroll
          for (int n = 0; n < 4; ++n) { p[n][v] = __expf(sacc[rg][n][v] - mt); ps += p[n][v]; }
#pragma unroll
          for (int msk = 1; msk < 16; msk <<= 1) ps += __shfl_xor(ps, msk);
          lrow[rg][v] = lrow[rg][v] * corr[v] + ps;
          mrow[rg][v] = mt;
        }
#pragma unroll
        for (int dn = 0; dn < 8; ++dn)
#pragma unroll
          for (int v = 0; v < 4; ++v) oacc[rg][dn][v] *= corr[v];
#pragma unroll
        for (int v = 0; v < 4; ++v)
#pragma unroll
          for (int n = 0; n < 4; ++n)
            Ps[w][(rg * 16 + lg * 4 + v) * 72 + n * 16 + lr] = (bf16)p[n][v];
      }
      // ---- PV: oacc[rg][dn] += P[rg] @ V^T; V direct from L2, reused x2 ----
#pragma unroll
      for (int kc = 0; kc < 2; ++kc) {
        bf16x8 pf0 = *(const bf16x8*)(&Ps[w][lr * 72 + kc * 32 + lg * 8]);
        bf16x8 pf1 = *(const bf16x8*)(&Ps[w][(16 + lr) * 72 + kc * 32 + lg * 8]);
#pragma unroll
        for (int dn = 0; dn < 8; ++dn) {
          int d = dn * 16 + lr;
          bf16x8 vf = *(const bf16x8*)(Vb + (long)d * S_ + k0 + kc * 32 + lg * 8);
          oacc[0][dn] = __builtin_amdgcn_mfma_f32_16x16x32_bf16(pf0, vf, oacc[0][dn], 0, 0, 0);
          oacc[1][dn] = __builtin_amdgcn_mfma_f32_16x16x32_bf16(pf1, vf, oacc[1][dn], 0, 0, 0);
        }
      }
    }
    __builtin_amdgcn_s_barrier();
  }
  // ---- epilogue ----
#pragma unroll
  for (int rg = 0; rg < 2; ++rg)
#pragma unroll
    for (int dn = 0; dn < 8; ++dn)
#pragma unroll
      for (int v = 0; v < 4; ++v) {
        int r = rg * 16 + lg * 4 + v;
        float o = oacc[rg][dn][v] / lrow[rg][v];
        att[((long)(b * S_ + qw + r)) * 2048 + h * 128 + dn * 16 + lr] = (bf16)o;
      }
}

extern "C" void kernel_launch(void* const* d_in, const int* in_sizes, int n_in,
                              void* d_out, int out_size, void* d_ws, size_t ws_size,
                              hipStream_t stream) {
  const float* x        = (const float*)d_in[0];
  const int* pos        = (const int*)d_in[1];   // harness passes integers as int32
  const float* Wqa      = (const float*)d_in[2];
  const float* g_qa     = (const float*)d_in[3];
  const float* Wqb      = (const float*)d_in[4];
  const float* Wkva     = (const float*)d_in[5];
  const float* g_kva    = (const float*)d_in[6];
  const float* Wkvb     = (const float*)d_in[7];
  const float* Wo       = (const float*)d_in[8];
  const float* cosT     = (const float*)d_in[9];
  const float* sinT     = (const float*)d_in[10];
  float* out            = (float*)d_out;

  // ---- workspace layout (persistent + phase-aliased transient region) ----
  size_t off = 0;
  char* wsp = (char*)d_ws;
  auto alloc = [&](size_t n) { void* p = wsp + off; off += (n + 255) & ~(size_t)255; return p; };
  bf16*  Wqa_t  = (bf16*) alloc((size_t)QR * HD * 2);
  bf16*  Wqb_t  = (bf16*) alloc((size_t)NQB * QR * 2);
  bf16*  Wkva_t = (bf16*) alloc((size_t)640 * HD * 2);
  bf16*  Wkvb_t = (bf16*) alloc((size_t)NKVB * KVR * 2);
  bf16*  Wo_t   = (bf16*) alloc((size_t)HD * HD * 2);
  bf16*  x_bf   = (bf16*) alloc((size_t)NTOK * HD * 2);
  bf16*  q_bhsd = (bf16*) alloc((size_t)B_ * NH * S_ * DQK * 2);
  bf16*  k_bhsd = (bf16*) alloc((size_t)B_ * NH * S_ * DQK * 2);
  bf16*  v_t    = (bf16*) alloc((size_t)B_ * NH * DV * S_ * 2);
  bf16*  att    = (bf16*) alloc((size_t)NTOK * 2048 * 2);
  char*  T      = (char*) alloc((size_t)50331648);
  bf16*  q_a = (bf16*)T;
  bf16*  q_n = (bf16*)(T + 12582912);
  bf16*  q_f = (bf16*)(T + 25165824);
  bf16*  kv_a = (bf16*)T;
  bf16*  kv_l = (bf16*)(T + 5242880);
  bf16*  kv_b = (bf16*)(T + 9437184);
  if (ws_size < off) return;

  cvt_bf16<<<(NTOK * HD / 4 + 255) / 256, 256, 0, stream>>>(x, x_bf, (long)NTOK * HD);
  transpose_cvt<<<dim3(QR / 32, HD / 32), 256, 0, stream>>>(Wqa, Wqa_t, HD, QR, QR);
  transpose_cvt<<<dim3(NQB / 32, QR / 32), 256, 0, stream>>>(Wqb, Wqb_t, QR, NQB, NQB);
  transpose_cvt<<<dim3(640 / 32, HD / 32), 256, 0, stream>>>(Wkva, Wkva_t, HD, 576, 640);
  transpose_cvt<<<dim3(NKVB / 32, KVR / 32), 256, 0, stream>>>(Wkvb, Wkvb_t, KVR, NKVB, NKVB);
  transpose_cvt<<<dim3(HD / 32, HD / 32), 256, 0, stream>>>(Wo, Wo_t, HD, HD, HD);
  // ---- Q path ----
  gemm_bf16<bf16><<<dim3(QR / 128, NTOK / 128), 256, 0, stream>>>(x_bf, Wqa_t, q_a, NTOK, QR, HD);
  rmsnorm_q<<<NTOK, 256, 0, stream>>>(q_a, g_qa, q_n);
  gemm_bf16<bf16><<<dim3(NQB / 128, NTOK / 128), 256, 0, stream>>>(q_n, Wqb_t, q_f, NTOK, NQB, QR);
  scatter_q<<<NTOK, 256, 0, stream>>>(q_f, pos, cosT, sinT, q_bhsd);
  // ---- KV path (reuses transient region) ----
  gemm_bf16<bf16><<<dim3(640 / 128, NTOK / 128), 256, 0, stream>>>(x_bf, Wkva_t, kv_a, NTOK, 640, HD);
  kv_prep<<<NTOK, 256, 0, stream>>>(kv_a, g_kva, pos, cosT, sinT, kv_l, k_bhsd);
  gemm_bf16<bf16><<<dim3(NKVB / 128, NTOK / 128), 256, 0, stream>>>(kv_l, Wkvb_t, kv_b, NTOK, NKVB, KVR);
  split_k<<<NTOK, 256, 0, stream>>>(kv_b, k_bhsd);
  v_trans<<<dim3(S_ / 32, DV / 32, B_ * NH), 256, 0, stream>>>(kv_b, v_t);
  // ---- attention + output projection ----
  flash3<<<512, 256, 0, stream>>>(q_bhsd, k_bhsd, v_t, att);
  gemm_bf16<float><<<dim3(HD / 128, NTOK / 128), 256, 0, stream>>>(att, Wo_t, out, NTOK, HD, HD);
}

// Round 5
// 385.482 us; speedup vs baseline: 1.3728x; 1.3728x over previous
//
#include <hip/hip_runtime.h>
#include <hip/hip_bf16.h>

typedef __bf16 bf16;
typedef __bf16 bf16x8 __attribute__((ext_vector_type(8)));
typedef __bf16 bf16x4 __attribute__((ext_vector_type(4)));
typedef float f32x4 __attribute__((ext_vector_type(4)));

#define B_    2
#define S_    2048
#define HD    2048
#define NH    16
#define DQK   192
#define DV    128
#define QR    1536
#define KVR   512
#define NTOK  4096
#define NKVB  4096   /* N_HEADS*(D_NOPE+D_V) */
#define NQB   3072   /* N_HEADS*D_QK */

static __device__ __forceinline__ void gload16(const void* g, void* l) {
  __builtin_amdgcn_global_load_lds(
      (const __attribute__((address_space(1))) void*)g,
      (__attribute__((address_space(3))) void*)l, 16, 0, 0);
}

// ---------------- f32 -> bf16 convert ----------------
__global__ __launch_bounds__(256) void cvt_bf16(const float* __restrict__ in,
                                                bf16* __restrict__ out, long n) {
  long i = ((long)blockIdx.x * 256 + threadIdx.x) * 4;
  if (i + 3 < n) {
    float4 v = *(const float4*)(in + i);
    bf16x4 o = {(bf16)v.x, (bf16)v.y, (bf16)v.z, (bf16)v.w};
    *(bf16x4*)(out + i) = o;
  }
}

// ---------------- transpose f32 [R][C] -> bf16 [Np][R], zero-pad rows >= C ----
__global__ __launch_bounds__(256) void transpose_cvt(const float* __restrict__ in,
                                                     bf16* __restrict__ out,
                                                     int R, int C, int Np) {
  __shared__ float tile[32][33];
  int c0 = blockIdx.x * 32;
  int r0 = blockIdx.y * 32;
  int tx = threadIdx.x & 31, ty = threadIdx.x >> 5;
#pragma unroll
  for (int i = 0; i < 4; ++i) {
    int r = r0 + ty + i * 8, c = c0 + tx;
    tile[ty + i * 8][tx] = (c < C) ? in[(long)r * C + c] : 0.f;
  }
  __syncthreads();
#pragma unroll
  for (int i = 0; i < 4; ++i) {
    int oc = c0 + ty + i * 8;
    if (oc < Np) out[(long)oc * R + r0 + tx] = (bf16)tile[tx][ty + i * 8];
  }
}

// ---------------- GEMM: C[M][N] = A[M][K] bf16 @ Bt[N][K] bf16 ----------------
// 128x128 tile, BK=64, 4 waves, gload16 with XOR chunk swizzle (slot=c^(r&7)),
// 2 barriers per 64-K (half the sync rounds of BK=32), 32 MFMA/wave per tile.
template <typename CT>
__global__ __launch_bounds__(256) void gemm_bf16(const bf16* __restrict__ A,
                                                 const bf16* __restrict__ Bt,
                                                 CT* __restrict__ C,
                                                 int M, int N, int K) {
  __shared__ bf16 As[128 * 64];
  __shared__ bf16 Bs[128 * 64];
  const int t = threadIdx.x;
  const int l = t & 63;
  const int w = t >> 6;
  const int m0 = blockIdx.y * 128;
  const int n0 = blockIdx.x * 128;
  const int wr = (w >> 1) * 64;
  const int wc = (w & 1) * 64;
  const int lr = l & 15;
  const int lg = l >> 4;

  f32x4 acc[4][4] = {};

  for (int k0 = 0; k0 < K; k0 += 64) {
    __syncthreads();
    // stage: 1024 16B-chunks per matrix, 4 rounds of 256; slot s holds
    // global chunk (row, sc^(row&7)) so swizzled reads are conflict-free.
#pragma unroll
    for (int j = 0; j < 4; ++j) {
      int s = j * 256 + t;
      int row = s >> 3, sc = s & 7;
      int c = sc ^ (row & 7);
      gload16(A  + (long)(m0 + row) * K + k0 + c * 8, As + (j * 256 + w * 64) * 8);
      gload16(Bt + (long)(n0 + row) * K + k0 + c * 8, Bs + (j * 256 + w * 64) * 8);
    }
    __syncthreads();
#pragma unroll
    for (int kh = 0; kh < 2; ++kh) {
      bf16x8 af[4], bfr[4];
#pragma unroll
      for (int m = 0; m < 4; ++m) {
        int row = wr + m * 16 + lr;
        af[m] = *(const bf16x8*)(As + row * 64 + (((kh * 4 + lg) ^ (row & 7)) << 3));
      }
#pragma unroll
      for (int n = 0; n < 4; ++n) {
        int row = wc + n * 16 + lr;
        bfr[n] = *(const bf16x8*)(Bs + row * 64 + (((kh * 4 + lg) ^ (row & 7)) << 3));
      }
#pragma unroll
      for (int m = 0; m < 4; ++m)
#pragma unroll
        for (int n = 0; n < 4; ++n)
          acc[m][n] = __builtin_amdgcn_mfma_f32_16x16x32_bf16(af[m], bfr[n], acc[m][n], 0, 0, 0);
    }
  }
#pragma unroll
  for (int m = 0; m < 4; ++m)
#pragma unroll
    for (int n = 0; n < 4; ++n)
#pragma unroll
      for (int v = 0; v < 4; ++v) {
        int row = m0 + wr + m * 16 + lg * 4 + v;
        int col = n0 + wc + n * 16 + lr;
        C[(long)row * N + col] = (CT)acc[m][n][v];
      }
}

// ---------------- RMSNorm (q path): [NTOK][QR] bf16 -> bf16 -------------------
__global__ __launch_bounds__(256) void rmsnorm_q(const bf16* __restrict__ in,
                                                 const float* __restrict__ g,
                                                 bf16* __restrict__ out) {
  int row = blockIdx.x;
  const bf16* x = in + (long)row * QR;
  float ss = 0.f;
  for (int j = threadIdx.x; j < QR; j += 256) { float v = (float)x[j]; ss += v * v; }
#pragma unroll
  for (int m = 1; m < 64; m <<= 1) ss += __shfl_xor(ss, m);
  __shared__ float red[4];
  if ((threadIdx.x & 63) == 0) red[threadIdx.x >> 6] = ss;
  __syncthreads();
  ss = red[0] + red[1] + red[2] + red[3];
  float rs = rsqrtf(ss / QR + 1e-5f);
  for (int j = threadIdx.x; j < QR; j += 256)
    out[(long)row * QR + j] = (bf16)((float)x[j] * rs * g[j]);
}

// ---------------- kv prep: RMSNorm latent + RoPE k_rope broadcast -------------
__global__ __launch_bounds__(256) void kv_prep(const bf16* __restrict__ kv_a,  // [NTOK][640]
                                               const float* __restrict__ g,    // [512]
                                               const int* __restrict__ pos,
                                               const float* __restrict__ cosT, // [S][32]
                                               const float* __restrict__ sinT,
                                               bf16* __restrict__ kv_l,        // [NTOK][512]
                                               bf16* __restrict__ k_bhsd) {    // [B][H][S][192]
  int row = blockIdx.x;
  int b = row / S_, s = row % S_;
  const bf16* x = kv_a + (long)row * 640;
  float ss = 0.f;
  for (int j = threadIdx.x; j < KVR; j += 256) { float v = (float)x[j]; ss += v * v; }
#pragma unroll
  for (int m = 1; m < 64; m <<= 1) ss += __shfl_xor(ss, m);
  __shared__ float red[4];
  if ((threadIdx.x & 63) == 0) red[threadIdx.x >> 6] = ss;
  __syncthreads();
  ss = red[0] + red[1] + red[2] + red[3];
  float rs = rsqrtf(ss / KVR + 1e-5f);
  for (int j = threadIdx.x; j < KVR; j += 256)
    kv_l[(long)row * KVR + j] = (bf16)((float)x[j] * rs * g[j]);
  if (threadIdx.x < 32) {
    int i = threadIdx.x;
    int p = pos[s] & (S_ - 1);
    float c = cosT[p * 32 + i], sn = sinT[p * 32 + i];
    float x0 = (float)x[512 + i], x1 = (float)x[544 + i];
    bf16 r0 = (bf16)(x0 * c - x1 * sn);
    bf16 r1 = (bf16)(x0 * sn + x1 * c);
    for (int h = 0; h < NH; ++h) {
      long base = (((long)(b * NH + h)) * S_ + s) * DQK;
      k_bhsd[base + 128 + i] = r0;
      k_bhsd[base + 160 + i] = r1;
    }
  }
}

// ---------------- q scatter v2: bf16x8 chunks; RoPE + SCALE -------------------
__global__ __launch_bounds__(384) void scatter_q(const bf16* __restrict__ q,
                                                 const int* __restrict__ pos,
                                                 const float* __restrict__ cosT,
                                                 const float* __restrict__ sinT,
                                                 bf16* __restrict__ q_bhsd) {
  const float SCALE = 0.07216878364870323f;  // 192^-0.5
  int row = blockIdx.x;
  int b = row >> 11, s = row & (S_ - 1);
  int p = pos[s] & (S_ - 1);
  const bf16* qr = q + (long)row * NQB;
  int j8 = threadIdx.x;               // 0..383 chunk index
  int h = j8 / 24, c = j8 % 24;
  bf16x8 ov;
  if (c < 16) {
    bf16x8 v = *(const bf16x8*)(qr + h * DQK + c * 8);
#pragma unroll
    for (int e = 0; e < 8; ++e) ov[e] = (bf16)((float)v[e] * SCALE);
  } else if (c < 20) {
    int i0 = (c - 16) * 8;
    bf16x8 lo = *(const bf16x8*)(qr + h * DQK + 128 + i0);
    bf16x8 hi = *(const bf16x8*)(qr + h * DQK + 160 + i0);
#pragma unroll
    for (int e = 0; e < 8; ++e) {
      float cs = cosT[p * 32 + i0 + e], sn = sinT[p * 32 + i0 + e];
      ov[e] = (bf16)(((float)lo[e] * cs - (float)hi[e] * sn) * SCALE);
    }
  } else {
    int i0 = (c - 20) * 8;
    bf16x8 lo = *(const bf16x8*)(qr + h * DQK + 128 + i0);
    bf16x8 hi = *(const bf16x8*)(qr + h * DQK + 160 + i0);
#pragma unroll
    for (int e = 0; e < 8; ++e) {
      float cs = cosT[p * 32 + i0 + e], sn = sinT[p * 32 + i0 + e];
      ov[e] = (bf16)(((float)lo[e] * sn + (float)hi[e] * cs) * SCALE);
    }
  }
  *(bf16x8*)(q_bhsd + (((long)(b * NH + h)) * S_ + s) * DQK + c * 8) = ov;
}

// ---------------- split k_nope v2: bf16x8, 1 chunk/thread ---------------------
__global__ __launch_bounds__(256) void split_k(const bf16* __restrict__ kv_b,
                                               bf16* __restrict__ k_bhsd) {
  int row = blockIdx.x;
  int b = row >> 11, s = row & (S_ - 1);
  int t = threadIdx.x;
  int h = t >> 4, d8 = t & 15;
  bf16x8 v = *(const bf16x8*)(kv_b + (long)row * NKVB + h * 256 + d8 * 8);
  *(bf16x8*)(k_bhsd + (((long)(b * NH + h)) * S_ + s) * DQK + d8 * 8) = v;
}

// ---------------- V transpose: kv_b v-part -> v_t [BH][128][S] bf16 -----------
__global__ __launch_bounds__(256) void v_trans(const bf16* __restrict__ kv_b,
                                               bf16* __restrict__ v_t) {
  __shared__ bf16 tile[32][33];
  int st = blockIdx.x, dt = blockIdx.y, bh = blockIdx.z;
  int b = bh >> 4, h = bh & 15;
  int tx = threadIdx.x & 31, ty = threadIdx.x >> 5;
#pragma unroll
  for (int i = 0; i < 4; ++i) {
    int s = st * 32 + ty + i * 8, d = dt * 32 + tx;
    tile[ty + i * 8][tx] = kv_b[((long)(b * S_ + s)) * NKVB + h * 256 + 128 + d];
  }
  __syncthreads();
#pragma unroll
  for (int i = 0; i < 4; ++i) {
    int d = dt * 32 + ty + i * 8, s = st * 32 + tx;
    v_t[((long)bh * DV + d) * S_ + s] = tile[tx][ty + i * 8];
  }
}

// ---------------- flash attention v2 (proven 116us): 4 waves, QBLK=64 ---------
#define QBLK 64
#define KVB  64
__global__ __launch_bounds__(256) void flash2(const bf16* __restrict__ q_bhsd,
                                              const bf16* __restrict__ k_bhsd,
                                              const bf16* __restrict__ v_t,
                                              bf16* __restrict__ att) {  // [NTOK][2048]
  __shared__ bf16 Ks[KVB * DQK];      // 24 KB, swizzled 16B chunks
  __shared__ bf16 Vs[DV * KVB];       // 16 KB, swizzled 16B chunks
  __shared__ bf16 Ps[4][16 * 72];     // 9 KB, per-wave P, padded to 72
  int bid = blockIdx.x;
  int bh = bid & 31;                  // head-of-batch: fixes XCD = bh%8
  int qt = 31 - (bid >> 5);           // heaviest (most k-tiles) first
  int b = bh >> 4, h = bh & 15;
  int q0 = qt * QBLK;
  int t = threadIdx.x;
  int w = t >> 6, l = t & 63;
  int lr = l & 15, lg = l >> 4;
  int qw = q0 + w * 16;               // this wave's first q row

  const bf16* Qb = q_bhsd + (long)bh * S_ * DQK;
  const bf16* Kb = k_bhsd + (long)bh * S_ * DQK;
  const bf16* Vb = v_t + (long)bh * DV * S_;

  bf16x8 qf[6];
#pragma unroll
  for (int t6 = 0; t6 < 6; ++t6)
    qf[t6] = *(const bf16x8*)(Qb + (long)(qw + lr) * DQK + t6 * 32 + lg * 8);

  f32x4 oacc[8] = {};
  float mrow[4] = {-1e30f, -1e30f, -1e30f, -1e30f};
  float lrow[4] = {0.f, 0.f, 0.f, 0.f};
  const int lr7 = lr & 7;

  int nkt = qt + 1;
  for (int kt = 0; kt < nkt; ++kt) {
    int k0 = kt * KVB;
    __syncthreads();
    // stage K: 1536 chunks (6 x 256); slot s holds global chunk (r, c^(r&7))
#pragma unroll
    for (int j = 0; j < 6; ++j) {
      int s = j * 256 + t;
      int r = s / 24, c1 = s - r * 24;
      int c = c1 ^ (r & 7);
      gload16(Kb + (long)(k0 + r) * DQK + c * 8, Ks + (j * 256 + w * 64) * 8);
    }
    // stage V: 1024 chunks (4 x 256)
#pragma unroll
    for (int j = 0; j < 4; ++j) {
      int s = j * 256 + t;
      int d = s >> 3, c1 = s & 7;
      int c = c1 ^ (d & 7);
      gload16(Vb + (long)d * S_ + k0 + c * 8, Vs + (j * 256 + w * 64) * 8);
    }
    __syncthreads();
    if (k0 > qw + 15) continue;       // fully masked for this wave

    // ---- QK^T: sacc[n] = scores[q=lg*4+v][k=n*16+lr] ----
    f32x4 sacc[4] = {};
#pragma unroll
    for (int n = 0; n < 4; ++n) {
      int rk = n * 16 + lr;
#pragma unroll
      for (int t6 = 0; t6 < 6; ++t6) {
        bf16x8 kf = *(const bf16x8*)(Ks + rk * DQK + (((t6 * 4 + lg) ^ lr7) << 3));
        sacc[n] = __builtin_amdgcn_mfma_f32_16x16x32_bf16(qf[t6], kf, sacc[n], 0, 0, 0);
      }
    }
    // ---- causal mask (diagonal tiles only) ----
    if (k0 + KVB - 1 > qw) {
#pragma unroll
      for (int n = 0; n < 4; ++n)
#pragma unroll
        for (int v = 0; v < 4; ++v) {
          int r = lg * 4 + v, c = n * 16 + lr;
          if (k0 + c > qw + r) sacc[n][v] = -1e30f;
        }
    }
    // ---- online softmax ----
    float corr[4], p[4][4];
#pragma unroll
    for (int v = 0; v < 4; ++v) {
      float mv = fmaxf(fmaxf(sacc[0][v], sacc[1][v]), fmaxf(sacc[2][v], sacc[3][v]));
#pragma unroll
      for (int msk = 1; msk < 16; msk <<= 1) mv = fmaxf(mv, __shfl_xor(mv, msk));
      float mt = fmaxf(mrow[v], mv);
      corr[v] = __expf(mrow[v] - mt);
      float ps = 0.f;
#pragma unroll
      for (int n = 0; n < 4; ++n) { p[n][v] = __expf(sacc[n][v] - mt); ps += p[n][v]; }
#pragma unroll
      for (int msk = 1; msk < 16; msk <<= 1) ps += __shfl_xor(ps, msk);
      lrow[v] = lrow[v] * corr[v] + ps;
      mrow[v] = mt;
    }
#pragma unroll
    for (int dn = 0; dn < 8; ++dn)
#pragma unroll
      for (int v = 0; v < 4; ++v) oacc[dn][v] *= corr[v];
    // ---- P -> LDS (per-wave, padded) ----
#pragma unroll
    for (int v = 0; v < 4; ++v)
#pragma unroll
      for (int n = 0; n < 4; ++n)
        Ps[w][(lg * 4 + v) * 72 + n * 16 + lr] = (bf16)p[n][v];
    // ---- PV: oacc[dn] += P[16x64] @ V^T[d=dn*16+lr][k] ----
#pragma unroll
    for (int kc = 0; kc < 2; ++kc) {
      bf16x8 pf = *(const bf16x8*)(Ps[w] + lr * 72 + kc * 32 + lg * 8);
#pragma unroll
      for (int dn = 0; dn < 8; ++dn) {
        int d = dn * 16 + lr;
        bf16x8 vf = *(const bf16x8*)(Vs + d * KVB + (((kc * 4 + lg) ^ lr7) << 3));
        oacc[dn] = __builtin_amdgcn_mfma_f32_16x16x32_bf16(pf, vf, oacc[dn], 0, 0, 0);
      }
    }
  }
  // ---- epilogue ----
#pragma unroll
  for (int dn = 0; dn < 8; ++dn)
#pragma unroll
    for (int v = 0; v < 4; ++v) {
      int r = lg * 4 + v;
      float o = oacc[dn][v] / lrow[v];
      att[((long)(b * S_ + qw + r)) * 2048 + h * 128 + dn * 16 + lr] = (bf16)o;
    }
}

extern "C" void kernel_launch(void* const* d_in, const int* in_sizes, int n_in,
                              void* d_out, int out_size, void* d_ws, size_t ws_size,
                              hipStream_t stream) {
  const float* x        = (const float*)d_in[0];
  const int* pos        = (const int*)d_in[1];   // harness passes integers as int32
  const float* Wqa      = (const float*)d_in[2];
  const float* g_qa     = (const float*)d_in[3];
  const float* Wqb      = (const float*)d_in[4];
  const float* Wkva     = (const float*)d_in[5];
  const float* g_kva    = (const float*)d_in[6];
  const float* Wkvb     = (const float*)d_in[7];
  const float* Wo       = (const float*)d_in[8];
  const float* cosT     = (const float*)d_in[9];
  const float* sinT     = (const float*)d_in[10];
  float* out            = (float*)d_out;

  // ---- workspace layout (persistent + phase-aliased transient region) ----
  size_t off = 0;
  char* wsp = (char*)d_ws;
  auto alloc = [&](size_t n) { void* p = wsp + off; off += (n + 255) & ~(size_t)255; return p; };
  bf16*  Wqa_t  = (bf16*) alloc((size_t)QR * HD * 2);
  bf16*  Wqb_t  = (bf16*) alloc((size_t)NQB * QR * 2);
  bf16*  Wkva_t = (bf16*) alloc((size_t)640 * HD * 2);
  bf16*  Wkvb_t = (bf16*) alloc((size_t)NKVB * KVR * 2);
  bf16*  Wo_t   = (bf16*) alloc((size_t)HD * HD * 2);
  bf16*  x_bf   = (bf16*) alloc((size_t)NTOK * HD * 2);
  bf16*  q_bhsd = (bf16*) alloc((size_t)B_ * NH * S_ * DQK * 2);
  bf16*  k_bhsd = (bf16*) alloc((size_t)B_ * NH * S_ * DQK * 2);
  bf16*  v_t    = (bf16*) alloc((size_t)B_ * NH * DV * S_ * 2);
  bf16*  att    = (bf16*) alloc((size_t)NTOK * 2048 * 2);
  char*  T      = (char*) alloc((size_t)50331648);
  bf16*  q_a = (bf16*)T;
  bf16*  q_n = (bf16*)(T + 12582912);
  bf16*  q_f = (bf16*)(T + 25165824);
  bf16*  kv_a = (bf16*)T;
  bf16*  kv_l = (bf16*)(T + 5242880);
  bf16*  kv_b = (bf16*)(T + 9437184);
  if (ws_size < off) return;

  cvt_bf16<<<(NTOK * HD / 4 + 255) / 256, 256, 0, stream>>>(x, x_bf, (long)NTOK * HD);
  transpose_cvt<<<dim3(QR / 32, HD / 32), 256, 0, stream>>>(Wqa, Wqa_t, HD, QR, QR);
  transpose_cvt<<<dim3(NQB / 32, QR / 32), 256, 0, stream>>>(Wqb, Wqb_t, QR, NQB, NQB);
  transpose_cvt<<<dim3(640 / 32, HD / 32), 256, 0, stream>>>(Wkva, Wkva_t, HD, 576, 640);
  transpose_cvt<<<dim3(NKVB / 32, KVR / 32), 256, 0, stream>>>(Wkvb, Wkvb_t, KVR, NKVB, NKVB);
  transpose_cvt<<<dim3(HD / 32, HD / 32), 256, 0, stream>>>(Wo, Wo_t, HD, HD, HD);
  // ---- Q path ----
  gemm_bf16<bf16><<<dim3(QR / 128, NTOK / 128), 256, 0, stream>>>(x_bf, Wqa_t, q_a, NTOK, QR, HD);
  rmsnorm_q<<<NTOK, 256, 0, stream>>>(q_a, g_qa, q_n);
  gemm_bf16<bf16><<<dim3(NQB / 128, NTOK / 128), 256, 0, stream>>>(q_n, Wqb_t, q_f, NTOK, NQB, QR);
  scatter_q<<<NTOK, 384, 0, stream>>>(q_f, pos, cosT, sinT, q_bhsd);
  // ---- KV path (reuses transient region) ----
  gemm_bf16<bf16><<<dim3(640 / 128, NTOK / 128), 256, 0, stream>>>(x_bf, Wkva_t, kv_a, NTOK, 640, HD);
  kv_prep<<<NTOK, 256, 0, stream>>>(kv_a, g_kva, pos, cosT, sinT, kv_l, k_bhsd);
  gemm_bf16<bf16><<<dim3(NKVB / 128, NTOK / 128), 256, 0, stream>>>(kv_l, Wkvb_t, kv_b, NTOK, NKVB, KVR);
  split_k<<<NTOK, 256, 0, stream>>>(kv_b, k_bhsd);
  v_trans<<<dim3(S_ / 32, DV / 32, B_ * NH), 256, 0, stream>>>(kv_b, v_t);
  // ---- attention + output projection ----
  flash2<<<1024, 256, 0, stream>>>(q_bhsd, k_bhsd, v_t, att);
  gemm_bf16<float><<<dim3(HD / 128, NTOK / 128), 256, 0, stream>>>(att, Wo_t, out, NTOK, HD, HD);
}

// Round 6
// 357.812 us; speedup vs baseline: 1.4790x; 1.0773x over previous
//
#include <hip/hip_runtime.h>
#include <hip/hip_bf16.h>

typedef __bf16 bf16;
typedef __bf16 bf16x8 __attribute__((ext_vector_type(8)));
typedef __bf16 bf16x4 __attribute__((ext_vector_type(4)));
typedef float f32x4 __attribute__((ext_vector_type(4)));

#define B_    2
#define S_    2048
#define HD    2048
#define NH    16
#define DQK   192
#define DV    128
#define QR    1536
#define KVR   512
#define NTOK  4096
#define NKVB  4096   /* N_HEADS*(D_NOPE+D_V) */
#define NQB   3072   /* N_HEADS*D_QK */
#define NQKVA 2176   /* QR + 640 (padded kv_a) */

static __device__ __forceinline__ void gload16(const void* g, void* l) {
  __builtin_amdgcn_global_load_lds(
      (const __attribute__((address_space(1))) void*)g,
      (__attribute__((address_space(3))) void*)l, 16, 0, 0);
}

// ---------------- f32 -> bf16 convert ----------------
__global__ __launch_bounds__(256) void cvt_bf16(const float* __restrict__ in,
                                                bf16* __restrict__ out, long n) {
  long i = ((long)blockIdx.x * 256 + threadIdx.x) * 4;
  if (i + 3 < n) {
    float4 v = *(const float4*)(in + i);
    bf16x4 o = {(bf16)v.x, (bf16)v.y, (bf16)v.z, (bf16)v.w};
    *(bf16x4*)(out + i) = o;
  }
}

// ---------------- transpose f32 [R][C] -> bf16 [Np][R], zero-pad rows >= C ----
__global__ __launch_bounds__(256) void transpose_cvt(const float* __restrict__ in,
                                                     bf16* __restrict__ out,
                                                     int R, int C, int Np) {
  __shared__ float tile[32][33];
  int c0 = blockIdx.x * 32;
  int r0 = blockIdx.y * 32;
  int tx = threadIdx.x & 31, ty = threadIdx.x >> 5;
#pragma unroll
  for (int i = 0; i < 4; ++i) {
    int r = r0 + ty + i * 8, c = c0 + tx;
    tile[ty + i * 8][tx] = (c < C) ? in[(long)r * C + c] : 0.f;
  }
  __syncthreads();
#pragma unroll
  for (int i = 0; i < 4; ++i) {
    int oc = c0 + ty + i * 8;
    if (oc < Np) out[(long)oc * R + r0 + tx] = (bf16)tile[tx][ty + i * 8];
  }
}

// ============ shared GEMM core: 128x128 tile, BK=64, XOR chunk swizzle ========
// Produces acc[4][4] (f32x4) for wave (wr,wc); caller-specific epilogue.
#define GEMM_CORE(A, Bt, K)                                                    \
  __shared__ bf16 As[128 * 64];                                                \
  __shared__ bf16 Bs[128 * 64];                                                \
  const int t = threadIdx.x;                                                   \
  const int l = t & 63;                                                        \
  const int w = t >> 6;                                                        \
  const int m0 = blockIdx.y * 128;                                             \
  const int n0 = blockIdx.x * 128;                                             \
  const int wr = (w >> 1) * 64;                                                \
  const int wc = (w & 1) * 64;                                                 \
  const int lr = l & 15;                                                       \
  const int lg = l >> 4;                                                       \
  f32x4 acc[4][4] = {};                                                        \
  for (int k0 = 0; k0 < (K); k0 += 64) {                                       \
    __syncthreads();                                                           \
    _Pragma("unroll")                                                          \
    for (int j = 0; j < 4; ++j) {                                              \
      int s = j * 256 + t;                                                     \
      int row = s >> 3, sc = s & 7;                                            \
      int c = sc ^ (row & 7);                                                  \
      gload16((A) + (long)(m0 + row) * (K) + k0 + c * 8,                       \
              As + (j * 256 + w * 64) * 8);                                    \
      gload16((Bt) + (long)(n0 + row) * (K) + k0 + c * 8,                      \
              Bs + (j * 256 + w * 64) * 8);                                    \
    }                                                                          \
    __syncthreads();                                                           \
    _Pragma("unroll")                                                          \
    for (int kh = 0; kh < 2; ++kh) {                                           \
      bf16x8 af[4], bfr[4];                                                    \
      _Pragma("unroll")                                                        \
      for (int m = 0; m < 4; ++m) {                                            \
        int row = wr + m * 16 + lr;                                            \
        af[m] = *(const bf16x8*)(As + row * 64 + (((kh * 4 + lg) ^ (row & 7)) << 3)); \
      }                                                                        \
      _Pragma("unroll")                                                        \
      for (int n = 0; n < 4; ++n) {                                            \
        int row = wc + n * 16 + lr;                                            \
        bfr[n] = *(const bf16x8*)(Bs + row * 64 + (((kh * 4 + lg) ^ (row & 7)) << 3)); \
      }                                                                        \
      _Pragma("unroll")                                                        \
      for (int m = 0; m < 4; ++m)                                              \
        _Pragma("unroll")                                                      \
        for (int n = 0; n < 4; ++n)                                            \
          acc[m][n] = __builtin_amdgcn_mfma_f32_16x16x32_bf16(af[m], bfr[n], acc[m][n], 0, 0, 0); \
    }                                                                          \
  }

// ---------------- generic GEMM: C[M][N] = A @ Bt^T ----------------------------
template <typename CT>
__global__ __launch_bounds__(256) void gemm_bf16(const bf16* __restrict__ A,
                                                 const bf16* __restrict__ Bt,
                                                 CT* __restrict__ C,
                                                 int M, int N, int K) {
  GEMM_CORE(A, Bt, K)
#pragma unroll
  for (int m = 0; m < 4; ++m)
#pragma unroll
    for (int n = 0; n < 4; ++n)
#pragma unroll
      for (int v = 0; v < 4; ++v) {
        int row = m0 + wr + m * 16 + lg * 4 + v;
        int col = n0 + wc + n * 16 + lr;
        C[(long)row * N + col] = (CT)acc[m][n][v];
      }
}

// ---------------- fused q_f GEMM: epilogue applies RoPE+SCALE -> q_bhsd -------
// N=3072 cols map to (h = c/192, jj = c%192); each 64-col wave-half is
// entirely nope (jj<128) or entirely rope; rope pairs are (n, n+2) in-thread.
__global__ __launch_bounds__(256) void gemm_qf(const bf16* __restrict__ A,
                                               const bf16* __restrict__ Bt,
                                               const int* __restrict__ pos,
                                               const float* __restrict__ cosT,
                                               const float* __restrict__ sinT,
                                               bf16* __restrict__ q_bhsd) {
  const float SCALE = 0.07216878364870323f;  // 192^-0.5
  GEMM_CORE(A, Bt, QR)
  int c0 = n0 + wc;
  int h = c0 / 192;
  int part = c0 - h * 192;            // 0, 64, or 128 (wave-uniform)
#pragma unroll
  for (int m = 0; m < 4; ++m)
#pragma unroll
    for (int v = 0; v < 4; ++v) {
      int row = m0 + wr + m * 16 + lg * 4 + v;
      int b = row >> 11, s = row & (S_ - 1);
      long base = ((long)(b * NH + h) * S_ + s) * DQK;
      if (part < 128) {
#pragma unroll
        for (int n = 0; n < 4; ++n)
          q_bhsd[base + part + n * 16 + lr] = (bf16)(acc[m][n][v] * SCALE);
      } else {
        int p = pos[s] & (S_ - 1);
        float c_lo = cosT[p * 32 + lr],      s_lo = sinT[p * 32 + lr];
        float c_hi = cosT[p * 32 + 16 + lr], s_hi = sinT[p * 32 + 16 + lr];
        float o0 = acc[m][0][v] * c_lo - acc[m][2][v] * s_lo;
        float o1 = acc[m][1][v] * c_hi - acc[m][3][v] * s_hi;
        float o2 = acc[m][0][v] * s_lo + acc[m][2][v] * c_lo;
        float o3 = acc[m][1][v] * s_hi + acc[m][3][v] * c_hi;
        q_bhsd[base + 128 + lr] = (bf16)(o0 * SCALE);
        q_bhsd[base + 144 + lr] = (bf16)(o1 * SCALE);
        q_bhsd[base + 160 + lr] = (bf16)(o2 * SCALE);
        q_bhsd[base + 176 + lr] = (bf16)(o3 * SCALE);
      }
    }
}

// ---------------- fused kv_b GEMM: k-part -> k_bhsd, v-part -> v_rows ---------
// N=4096 cols: h = c>>8, k-part if (c&255)<128; each 128-col block uniform.
__global__ __launch_bounds__(256) void gemm_kvb(const bf16* __restrict__ A,
                                                const bf16* __restrict__ Bt,
                                                bf16* __restrict__ k_bhsd,
                                                bf16* __restrict__ v_rows) {
  GEMM_CORE(A, Bt, KVR)
  int c0 = n0 + wc;
  int h = c0 >> 8;
  int dbase = c0 & 64;                // offset within the 128-wide half
  bool vpart = (c0 >> 7) & 1;
#pragma unroll
  for (int m = 0; m < 4; ++m)
#pragma unroll
    for (int v = 0; v < 4; ++v) {
      int row = m0 + wr + m * 16 + lg * 4 + v;
      int b = row >> 11, s = row & (S_ - 1);
      if (!vpart) {
        long base = ((long)(b * NH + h) * S_ + s) * DQK + dbase;
#pragma unroll
        for (int n = 0; n < 4; ++n)
          k_bhsd[base + n * 16 + lr] = (bf16)acc[m][n][v];
      } else {
        long base = (long)row * 2048 + h * 128 + dbase;
#pragma unroll
        for (int n = 0; n < 4; ++n)
          v_rows[base + n * 16 + lr] = (bf16)acc[m][n][v];
      }
    }
}

// ---------------- RMSNorm (q path): [NTOK][2176 (q cols 0..1535)] -> q_n ------
__global__ __launch_bounds__(192) void rmsnorm_q(const bf16* __restrict__ in,
                                                 const float* __restrict__ g,
                                                 bf16* __restrict__ out) {
  int row = blockIdx.x;
  int t = threadIdx.x;                // chunk 0..191
  const bf16* x = in + (long)row * NQKVA;
  bf16x8 vv = *(const bf16x8*)(x + t * 8);
  float vf[8]; float ss = 0.f;
#pragma unroll
  for (int e = 0; e < 8; ++e) { vf[e] = (float)vv[e]; ss += vf[e] * vf[e]; }
#pragma unroll
  for (int m = 1; m < 64; m <<= 1) ss += __shfl_xor(ss, m);
  __shared__ float red[3];
  if ((t & 63) == 0) red[t >> 6] = ss;
  __syncthreads();
  ss = red[0] + red[1] + red[2];
  float rs = rsqrtf(ss / QR + 1e-5f);
  bf16x8 o;
#pragma unroll
  for (int e = 0; e < 8; ++e) o[e] = (bf16)(vf[e] * rs * g[t * 8 + e]);
  *(bf16x8*)(out + (long)row * QR + t * 8) = o;
}

// ---------------- kv prep: RMSNorm latent + RoPE k_rope broadcast (1 wave) ----
__global__ __launch_bounds__(64) void kv_prep(const bf16* __restrict__ xa,   // [NTOK][2176]
                                              const float* __restrict__ g,   // [512]
                                              const int* __restrict__ pos,
                                              const float* __restrict__ cosT,
                                              const float* __restrict__ sinT,
                                              bf16* __restrict__ kv_l,       // [NTOK][512]
                                              bf16* __restrict__ k_bhsd) {   // [B][H][S][192]
  int row = blockIdx.x;
  int t = threadIdx.x;                // 0..63
  int b = row >> 11, s = row & (S_ - 1);
  const bf16* x = xa + (long)row * NQKVA + QR;   // latent at cols 1536..2047
  bf16x8 vv = *(const bf16x8*)(x + t * 8);
  float vf[8]; float ss = 0.f;
#pragma unroll
  for (int e = 0; e < 8; ++e) { vf[e] = (float)vv[e]; ss += vf[e] * vf[e]; }
#pragma unroll
  for (int m = 1; m < 64; m <<= 1) ss += __shfl_xor(ss, m);
  float rs = rsqrtf(ss / KVR + 1e-5f);
  bf16x8 o;
#pragma unroll
  for (int e = 0; e < 8; ++e) o[e] = (bf16)(vf[e] * rs * g[t * 8 + e]);
  *(bf16x8*)(kv_l + (long)row * KVR + t * 8) = o;
  // rope: cols 2048..2111 of xa
  __shared__ bf16 rope_s[64];
  if (t < 32) {
    int p = pos[s] & (S_ - 1);
    float c = cosT[p * 32 + t], sn = sinT[p * 32 + t];
    float x0 = (float)x[512 + t], x1 = (float)x[544 + t];
    rope_s[t] = (bf16)(x0 * c - x1 * sn);
    rope_s[32 + t] = (bf16)(x0 * sn + x1 * c);
  }
  __syncthreads();
  bf16x8 rv = *(const bf16x8*)&rope_s[(t & 7) * 8];
  long base0 = ((long)(b * NH + (t >> 3)) * S_ + s) * DQK + 128 + (t & 7) * 8;
  long base1 = ((long)(b * NH + 8 + (t >> 3)) * S_ + s) * DQK + 128 + (t & 7) * 8;
  *(bf16x8*)(k_bhsd + base0) = rv;
  *(bf16x8*)(k_bhsd + base1) = rv;
}

// ---------------- V transpose: v_rows [NTOK][2048] -> v_t [BH][128][S] --------
__global__ __launch_bounds__(256) void v_trans(const bf16* __restrict__ v_rows,
                                               bf16* __restrict__ v_t) {
  __shared__ bf16 tile[32][33];
  int st = blockIdx.x, dt = blockIdx.y, bh = blockIdx.z;
  int b = bh >> 4, h = bh & 15;
  int tx = threadIdx.x & 31, ty = threadIdx.x >> 5;
#pragma unroll
  for (int i = 0; i < 4; ++i) {
    int s = st * 32 + ty + i * 8, d = dt * 32 + tx;
    tile[ty + i * 8][tx] = v_rows[((long)(b * S_ + s)) * 2048 + h * 128 + d];
  }
  __syncthreads();
#pragma unroll
  for (int i = 0; i < 4; ++i) {
    int d = dt * 32 + ty + i * 8, s = st * 32 + tx;
    v_t[((long)bh * DV + d) * S_ + s] = tile[tx][ty + i * 8];
  }
}

// ---------------- flash attention v2 (proven 116us): 4 waves, QBLK=64 ---------
#define QBLK 64
#define KVB  64
__global__ __launch_bounds__(256) void flash2(const bf16* __restrict__ q_bhsd,
                                              const bf16* __restrict__ k_bhsd,
                                              const bf16* __restrict__ v_t,
                                              bf16* __restrict__ att) {  // [NTOK][2048]
  __shared__ bf16 Ks[KVB * DQK];      // 24 KB, swizzled 16B chunks
  __shared__ bf16 Vs[DV * KVB];       // 16 KB, swizzled 16B chunks
  __shared__ bf16 Ps[4][16 * 72];     // 9 KB, per-wave P, padded to 72
  int bid = blockIdx.x;
  int bh = bid & 31;                  // head-of-batch: fixes XCD = bh%8
  int qt = 31 - (bid >> 5);           // heaviest (most k-tiles) first
  int b = bh >> 4, h = bh & 15;
  int q0 = qt * QBLK;
  int t = threadIdx.x;
  int w = t >> 6, l = t & 63;
  int lr = l & 15, lg = l >> 4;
  int qw = q0 + w * 16;               // this wave's first q row

  const bf16* Qb = q_bhsd + (long)bh * S_ * DQK;
  const bf16* Kb = k_bhsd + (long)bh * S_ * DQK;
  const bf16* Vb = v_t + (long)bh * DV * S_;

  bf16x8 qf[6];
#pragma unroll
  for (int t6 = 0; t6 < 6; ++t6)
    qf[t6] = *(const bf16x8*)(Qb + (long)(qw + lr) * DQK + t6 * 32 + lg * 8);

  f32x4 oacc[8] = {};
  float mrow[4] = {-1e30f, -1e30f, -1e30f, -1e30f};
  float lrow[4] = {0.f, 0.f, 0.f, 0.f};
  const int lr7 = lr & 7;

  int nkt = qt + 1;
  for (int kt = 0; kt < nkt; ++kt) {
    int k0 = kt * KVB;
    __syncthreads();
    // stage K: 1536 chunks (6 x 256); slot s holds global chunk (r, c^(r&7))
#pragma unroll
    for (int j = 0; j < 6; ++j) {
      int s = j * 256 + t;
      int r = s / 24, c1 = s - r * 24;
      int c = c1 ^ (r & 7);
      gload16(Kb + (long)(k0 + r) * DQK + c * 8, Ks + (j * 256 + w * 64) * 8);
    }
    // stage V: 1024 chunks (4 x 256)
#pragma unroll
    for (int j = 0; j < 4; ++j) {
      int s = j * 256 + t;
      int d = s >> 3, c1 = s & 7;
      int c = c1 ^ (d & 7);
      gload16(Vb + (long)d * S_ + k0 + c * 8, Vs + (j * 256 + w * 64) * 8);
    }
    __syncthreads();
    if (k0 > qw + 15) continue;       // fully masked for this wave

    // ---- QK^T: sacc[n] = scores[q=lg*4+v][k=n*16+lr] ----
    f32x4 sacc[4] = {};
#pragma unroll
    for (int n = 0; n < 4; ++n) {
      int rk = n * 16 + lr;
#pragma unroll
      for (int t6 = 0; t6 < 6; ++t6) {
        bf16x8 kf = *(const bf16x8*)(Ks + rk * DQK + (((t6 * 4 + lg) ^ lr7) << 3));
        sacc[n] = __builtin_amdgcn_mfma_f32_16x16x32_bf16(qf[t6], kf, sacc[n], 0, 0, 0);
      }
    }
    // ---- causal mask (diagonal tiles only) ----
    if (k0 + KVB - 1 > qw) {
#pragma unroll
      for (int n = 0; n < 4; ++n)
#pragma unroll
        for (int v = 0; v < 4; ++v) {
          int r = lg * 4 + v, c = n * 16 + lr;
          if (k0 + c > qw + r) sacc[n][v] = -1e30f;
        }
    }
    // ---- online softmax ----
    float corr[4], p[4][4];
#pragma unroll
    for (int v = 0; v < 4; ++v) {
      float mv = fmaxf(fmaxf(sacc[0][v], sacc[1][v]), fmaxf(sacc[2][v], sacc[3][v]));
#pragma unroll
      for (int msk = 1; msk < 16; msk <<= 1) mv = fmaxf(mv, __shfl_xor(mv, msk));
      float mt = fmaxf(mrow[v], mv);
      corr[v] = __expf(mrow[v] - mt);
      float ps = 0.f;
#pragma unroll
      for (int n = 0; n < 4; ++n) { p[n][v] = __expf(sacc[n][v] - mt); ps += p[n][v]; }
#pragma unroll
      for (int msk = 1; msk < 16; msk <<= 1) ps += __shfl_xor(ps, msk);
      lrow[v] = lrow[v] * corr[v] + ps;
      mrow[v] = mt;
    }
#pragma unroll
    for (int dn = 0; dn < 8; ++dn)
#pragma unroll
      for (int v = 0; v < 4; ++v) oacc[dn][v] *= corr[v];
    // ---- P -> LDS (per-wave, padded) ----
#pragma unroll
    for (int v = 0; v < 4; ++v)
#pragma unroll
      for (int n = 0; n < 4; ++n)
        Ps[w][(lg * 4 + v) * 72 + n * 16 + lr] = (bf16)p[n][v];
    // ---- PV: oacc[dn] += P[16x64] @ V^T[d=dn*16+lr][k] ----
#pragma unroll
    for (int kc = 0; kc < 2; ++kc) {
      bf16x8 pf = *(const bf16x8*)(Ps[w] + lr * 72 + kc * 32 + lg * 8);
#pragma unroll
      for (int dn = 0; dn < 8; ++dn) {
        int d = dn * 16 + lr;
        bf16x8 vf = *(const bf16x8*)(Vs + d * KVB + (((kc * 4 + lg) ^ lr7) << 3));
        oacc[dn] = __builtin_amdgcn_mfma_f32_16x16x32_bf16(pf, vf, oacc[dn], 0, 0, 0);
      }
    }
  }
  // ---- epilogue ----
#pragma unroll
  for (int dn = 0; dn < 8; ++dn)
#pragma unroll
    for (int v = 0; v < 4; ++v) {
      int r = lg * 4 + v;
      float o = oacc[dn][v] / lrow[v];
      att[((long)(b * S_ + qw + r)) * 2048 + h * 128 + dn * 16 + lr] = (bf16)o;
    }
}

extern "C" void kernel_launch(void* const* d_in, const int* in_sizes, int n_in,
                              void* d_out, int out_size, void* d_ws, size_t ws_size,
                              hipStream_t stream) {
  const float* x        = (const float*)d_in[0];
  const int* pos        = (const int*)d_in[1];   // harness passes integers as int32
  const float* Wqa      = (const float*)d_in[2];
  const float* g_qa     = (const float*)d_in[3];
  const float* Wqb      = (const float*)d_in[4];
  const float* Wkva     = (const float*)d_in[5];
  const float* g_kva    = (const float*)d_in[6];
  const float* Wkvb     = (const float*)d_in[7];
  const float* Wo       = (const float*)d_in[8];
  const float* cosT     = (const float*)d_in[9];
  const float* sinT     = (const float*)d_in[10];
  float* out            = (float*)d_out;

  // ---- workspace layout ----
  size_t off = 0;
  char* wsp = (char*)d_ws;
  auto alloc = [&](size_t n) { void* p = wsp + off; off += (n + 255) & ~(size_t)255; return p; };
  bf16*  Wqa_t  = (bf16*) alloc((size_t)QR * HD * 2);      // contiguous with
  bf16*  Wkva_t = (bf16*) alloc((size_t)640 * HD * 2);     //  ... Wqa_t (concat Bt)
  bf16*  Wqb_t  = (bf16*) alloc((size_t)NQB * QR * 2);
  bf16*  Wkvb_t = (bf16*) alloc((size_t)NKVB * KVR * 2);
  bf16*  Wo_t   = (bf16*) alloc((size_t)HD * HD * 2);
  bf16*  x_bf   = (bf16*) alloc((size_t)NTOK * HD * 2);
  bf16*  q_bhsd = (bf16*) alloc((size_t)B_ * NH * S_ * DQK * 2);
  bf16*  k_bhsd = (bf16*) alloc((size_t)B_ * NH * S_ * DQK * 2);
  bf16*  v_rows = (bf16*) alloc((size_t)NTOK * 2048 * 2);
  bf16*  v_t    = (bf16*) alloc((size_t)B_ * NH * DV * S_ * 2);
  bf16*  att    = (bf16*) alloc((size_t)NTOK * 2048 * 2);
  char*  T      = (char*) alloc((size_t)33554432);         // 32 MB transient
  bf16*  xa  = (bf16*)T;                        // [NTOK][2176] = 17.8 MB
  bf16*  q_n = (bf16*)(T + 18874368);           // [NTOK][1536] = 12.6 MB
  bf16*  kv_l = (bf16*)(T + 18874368);          // [NTOK][512] after q path... 
  // NOTE: q_n is consumed by gemm_qf before kv_l is written; but kv_l aliases
  // q_n's region while xa (still needed by kv_prep) stays intact.
  if (ws_size < off) return;

  cvt_bf16<<<(NTOK * HD / 4 + 255) / 256, 256, 0, stream>>>(x, x_bf, (long)NTOK * HD);
  transpose_cvt<<<dim3(QR / 32, HD / 32), 256, 0, stream>>>(Wqa, Wqa_t, HD, QR, QR);
  transpose_cvt<<<dim3(640 / 32, HD / 32), 256, 0, stream>>>(Wkva, Wkva_t, HD, 576, 640);
  transpose_cvt<<<dim3(NQB / 32, QR / 32), 256, 0, stream>>>(Wqb, Wqb_t, QR, NQB, NQB);
  transpose_cvt<<<dim3(NKVB / 32, KVR / 32), 256, 0, stream>>>(Wkvb, Wkvb_t, KVR, NKVB, NKVB);
  transpose_cvt<<<dim3(HD / 32, HD / 32), 256, 0, stream>>>(Wo, Wo_t, HD, HD, HD);
  // ---- combined first-stage GEMM: xa = x_bf @ [Wqa | Wkva] ----
  gemm_bf16<bf16><<<dim3(NQKVA / 128, NTOK / 128), 256, 0, stream>>>(x_bf, Wqa_t, xa, NTOK, NQKVA, HD);
  // ---- Q path ----
  rmsnorm_q<<<NTOK, 192, 0, stream>>>(xa, g_qa, q_n);
  gemm_qf<<<dim3(NQB / 128, NTOK / 128), 256, 0, stream>>>(q_n, Wqb_t, pos, cosT, sinT, q_bhsd);
  // ---- KV path ----
  kv_prep<<<NTOK, 64, 0, stream>>>(xa, g_kva, pos, cosT, sinT, kv_l, k_bhsd);
  gemm_kvb<<<dim3(NKVB / 128, NTOK / 128), 256, 0, stream>>>(kv_l, Wkvb_t, k_bhsd, v_rows);
  v_trans<<<dim3(S_ / 32, DV / 32, B_ * NH), 256, 0, stream>>>(v_rows, v_t);
  // ---- attention + output projection ----
  flash2<<<1024, 256, 0, stream>>>(q_bhsd, k_bhsd, v_t, att);
  gemm_bf16<float><<<dim3(HD / 128, NTOK / 128), 256, 0, stream>>>(att, Wo_t, out, NTOK, HD, HD);
}

// Round 8
// 334.786 us; speedup vs baseline: 1.5807x; 1.0688x over previous
//
#include <hip/hip_runtime.h>
#include <hip/hip_bf16.h>

typedef __bf16 bf16;
typedef __bf16 bf16x8 __attribute__((ext_vector_type(8)));
typedef __bf16 bf16x4 __attribute__((ext_vector_type(4)));
typedef float f32x4 __attribute__((ext_vector_type(4)));

#define B_    2
#define S_    2048
#define HD    2048
#define NH    16
#define DQK   192
#define DV    128
#define QR    1536
#define KVR   512
#define NTOK  4096
#define NKVB  4096   /* N_HEADS*(D_NOPE+D_V) */
#define NQB   3072   /* N_HEADS*D_QK */
#define NQKVA 2176   /* QR + 640 (padded kv_a) */

#define EXP2F(x) __builtin_amdgcn_exp2f(x)

static __device__ __forceinline__ void gload16(const void* g, void* l) {
  __builtin_amdgcn_global_load_lds(
      (const __attribute__((address_space(1))) void*)g,
      (__attribute__((address_space(3))) void*)l, 16, 0, 0);
}

// ---------------- f32 -> bf16 convert ----------------
__global__ __launch_bounds__(256) void cvt_bf16(const float* __restrict__ in,
                                                bf16* __restrict__ out, long n) {
  long i = ((long)blockIdx.x * 256 + threadIdx.x) * 4;
  if (i + 3 < n) {
    float4 v = *(const float4*)(in + i);
    bf16x4 o = {(bf16)v.x, (bf16)v.y, (bf16)v.z, (bf16)v.w};
    *(bf16x4*)(out + i) = o;
  }
}

// ---------------- transpose f32 [R][C] -> bf16 [Np][R], zero-pad rows >= C ----
__global__ __launch_bounds__(256) void transpose_cvt(const float* __restrict__ in,
                                                     bf16* __restrict__ out,
                                                     int R, int C, int Np) {
  __shared__ float tile[32][33];
  int c0 = blockIdx.x * 32;
  int r0 = blockIdx.y * 32;
  int tx = threadIdx.x & 31, ty = threadIdx.x >> 5;
#pragma unroll
  for (int i = 0; i < 4; ++i) {
    int r = r0 + ty + i * 8, c = c0 + tx;
    tile[ty + i * 8][tx] = (c < C) ? in[(long)r * C + c] : 0.f;
  }
  __syncthreads();
#pragma unroll
  for (int i = 0; i < 4; ++i) {
    int oc = c0 + ty + i * 8;
    if (oc < Np) out[(long)oc * R + r0 + tx] = (bf16)tile[tx][ty + i * 8];
  }
}

// ============ shared GEMM core: 128x128 tile, BK=64, XOR chunk swizzle ========
#define GEMM_CORE(A, Bt, K)                                                    \
  __shared__ bf16 As[128 * 64];                                                \
  __shared__ bf16 Bs[128 * 64];                                                \
  const int t = threadIdx.x;                                                   \
  const int l = t & 63;                                                        \
  const int w = t >> 6;                                                        \
  const int m0 = blockIdx.y * 128;                                             \
  const int n0 = blockIdx.x * 128;                                             \
  const int wr = (w >> 1) * 64;                                                \
  const int wc = (w & 1) * 64;                                                 \
  const int lr = l & 15;                                                       \
  const int lg = l >> 4;                                                       \
  f32x4 acc[4][4] = {};                                                        \
  for (int k0 = 0; k0 < (K); k0 += 64) {                                       \
    __syncthreads();                                                           \
    _Pragma("unroll")                                                          \
    for (int j = 0; j < 4; ++j) {                                              \
      int s = j * 256 + t;                                                     \
      int row = s >> 3, sc = s & 7;                                            \
      int c = sc ^ (row & 7);                                                  \
      gload16((A) + (long)(m0 + row) * (K) + k0 + c * 8,                       \
              As + (j * 256 + w * 64) * 8);                                    \
      gload16((Bt) + (long)(n0 + row) * (K) + k0 + c * 8,                      \
              Bs + (j * 256 + w * 64) * 8);                                    \
    }                                                                          \
    __syncthreads();                                                           \
    _Pragma("unroll")                                                          \
    for (int kh = 0; kh < 2; ++kh) {                                           \
      bf16x8 af[4], bfr[4];                                                    \
      _Pragma("unroll")                                                        \
      for (int m = 0; m < 4; ++m) {                                            \
        int row = wr + m * 16 + lr;                                            \
        af[m] = *(const bf16x8*)(As + row * 64 + (((kh * 4 + lg) ^ (row & 7)) << 3)); \
      }                                                                        \
      _Pragma("unroll")                                                        \
      for (int n = 0; n < 4; ++n) {                                            \
        int row = wc + n * 16 + lr;                                            \
        bfr[n] = *(const bf16x8*)(Bs + row * 64 + (((kh * 4 + lg) ^ (row & 7)) << 3)); \
      }                                                                        \
      _Pragma("unroll")                                                        \
      for (int m = 0; m < 4; ++m)                                              \
        _Pragma("unroll")                                                      \
        for (int n = 0; n < 4; ++n)                                            \
          acc[m][n] = __builtin_amdgcn_mfma_f32_16x16x32_bf16(af[m], bfr[n], acc[m][n], 0, 0, 0); \
    }                                                                          \
  }

// ---------------- generic GEMM: C[M][N] = A @ Bt^T ----------------------------
template <typename CT>
__global__ __launch_bounds__(256) void gemm_bf16(const bf16* __restrict__ A,
                                                 const bf16* __restrict__ Bt,
                                                 CT* __restrict__ C,
                                                 int M, int N, int K) {
  GEMM_CORE(A, Bt, K)
#pragma unroll
  for (int m = 0; m < 4; ++m)
#pragma unroll
    for (int n = 0; n < 4; ++n)
#pragma unroll
      for (int v = 0; v < 4; ++v) {
        int row = m0 + wr + m * 16 + lg * 4 + v;
        int col = n0 + wc + n * 16 + lr;
        C[(long)row * N + col] = (CT)acc[m][n][v];
      }
}

// ---------------- fused q_f GEMM: epilogue applies RoPE + SCALE*LOG2E ---------
// (flash uses exp2; fold log2(e) into the q scale so scores are log2-domain)
__global__ __launch_bounds__(256) void gemm_qf(const bf16* __restrict__ A,
                                               const bf16* __restrict__ Bt,
                                               const int* __restrict__ pos,
                                               const float* __restrict__ cosT,
                                               const float* __restrict__ sinT,
                                               bf16* __restrict__ q_bhsd) {
  const float SCALE = 0.07216878364870323f * 1.4426950408889634f;
  GEMM_CORE(A, Bt, QR)
  int c0 = n0 + wc;
  int h = c0 / 192;
  int part = c0 - h * 192;            // 0, 64, or 128 (wave-uniform)
#pragma unroll
  for (int m = 0; m < 4; ++m)
#pragma unroll
    for (int v = 0; v < 4; ++v) {
      int row = m0 + wr + m * 16 + lg * 4 + v;
      int b = row >> 11, s = row & (S_ - 1);
      long base = ((long)(b * NH + h) * S_ + s) * DQK;
      if (part < 128) {
#pragma unroll
        for (int n = 0; n < 4; ++n)
          q_bhsd[base + part + n * 16 + lr] = (bf16)(acc[m][n][v] * SCALE);
      } else {
        int p = pos[s] & (S_ - 1);
        float c_lo = cosT[p * 32 + lr],      s_lo = sinT[p * 32 + lr];
        float c_hi = cosT[p * 32 + 16 + lr], s_hi = sinT[p * 32 + 16 + lr];
        float o0 = acc[m][0][v] * c_lo - acc[m][2][v] * s_lo;
        float o1 = acc[m][1][v] * c_hi - acc[m][3][v] * s_hi;
        float o2 = acc[m][0][v] * s_lo + acc[m][2][v] * c_lo;
        float o3 = acc[m][1][v] * s_hi + acc[m][3][v] * c_hi;
        q_bhsd[base + 128 + lr] = (bf16)(o0 * SCALE);
        q_bhsd[base + 144 + lr] = (bf16)(o1 * SCALE);
        q_bhsd[base + 160 + lr] = (bf16)(o2 * SCALE);
        q_bhsd[base + 176 + lr] = (bf16)(o3 * SCALE);
      }
    }
}

// ---------------- fused kv_b GEMM: k-part -> k_bhsd, v-part -> v_rows ---------
__global__ __launch_bounds__(256) void gemm_kvb(const bf16* __restrict__ A,
                                                const bf16* __restrict__ Bt,
                                                bf16* __restrict__ k_bhsd,
                                                bf16* __restrict__ v_rows) {
  GEMM_CORE(A, Bt, KVR)
  int c0 = n0 + wc;
  int h = c0 >> 8;
  int dbase = c0 & 64;
  bool vpart = (c0 >> 7) & 1;
#pragma unroll
  for (int m = 0; m < 4; ++m)
#pragma unroll
    for (int v = 0; v < 4; ++v) {
      int row = m0 + wr + m * 16 + lg * 4 + v;
      int b = row >> 11, s = row & (S_ - 1);
      if (!vpart) {
        long base = ((long)(b * NH + h) * S_ + s) * DQK + dbase;
#pragma unroll
        for (int n = 0; n < 4; ++n)
          k_bhsd[base + n * 16 + lr] = (bf16)acc[m][n][v];
      } else {
        long base = (long)row * 2048 + h * 128 + dbase;
#pragma unroll
        for (int n = 0; n < 4; ++n)
          v_rows[base + n * 16 + lr] = (bf16)acc[m][n][v];
      }
    }
}

// ---------------- merged norm+prep: waves 0-2 q-RMSNorm, wave 3 kv+rope -------
__global__ __launch_bounds__(256) void norm_prep(const bf16* __restrict__ xa,   // [NTOK][2176]
                                                 const float* __restrict__ g_qa,
                                                 const float* __restrict__ g_kva,
                                                 const int* __restrict__ pos,
                                                 const float* __restrict__ cosT,
                                                 const float* __restrict__ sinT,
                                                 bf16* __restrict__ q_n,       // [NTOK][1536]
                                                 bf16* __restrict__ kv_l,      // [NTOK][512]
                                                 bf16* __restrict__ k_bhsd) {  // [B][H][S][192]
  int row = blockIdx.x;
  int t = threadIdx.x;
  int b = row >> 11, s = row & (S_ - 1);
  const bf16* xr = xa + (long)row * NQKVA;
  __shared__ float red[3];
  __shared__ bf16 rope_s[64];
  float vf[8];
  if (t < 192) {
    bf16x8 vv = *(const bf16x8*)(xr + t * 8);
    float ss = 0.f;
#pragma unroll
    for (int e = 0; e < 8; ++e) { vf[e] = (float)vv[e]; ss += vf[e] * vf[e]; }
#pragma unroll
    for (int m = 1; m < 64; m <<= 1) ss += __shfl_xor(ss, m);
    if ((t & 63) == 0) red[t >> 6] = ss;
  } else {
    int tt = t - 192;
    const bf16* xl = xr + QR;
    bf16x8 vv = *(const bf16x8*)(xl + tt * 8);
    float ss = 0.f;
#pragma unroll
    for (int e = 0; e < 8; ++e) { vf[e] = (float)vv[e]; ss += vf[e] * vf[e]; }
#pragma unroll
    for (int m = 1; m < 64; m <<= 1) ss += __shfl_xor(ss, m);
    float rs = rsqrtf(ss / KVR + 1e-5f);
    bf16x8 o;
#pragma unroll
    for (int e = 0; e < 8; ++e) o[e] = (bf16)(vf[e] * rs * g_kva[tt * 8 + e]);
    *(bf16x8*)(kv_l + (long)row * KVR + tt * 8) = o;
    if (tt < 32) {
      int p = pos[s] & (S_ - 1);
      float c = cosT[p * 32 + tt], sn = sinT[p * 32 + tt];
      float x0 = (float)xl[512 + tt], x1 = (float)xl[544 + tt];
      rope_s[tt] = (bf16)(x0 * c - x1 * sn);
      rope_s[32 + tt] = (bf16)(x0 * sn + x1 * c);
    }
  }
  __syncthreads();
  if (t < 192) {
    float ss = red[0] + red[1] + red[2];
    float rs = rsqrtf(ss / QR + 1e-5f);
    bf16x8 o;
#pragma unroll
    for (int e = 0; e < 8; ++e) o[e] = (bf16)(vf[e] * rs * g_qa[t * 8 + e]);
    *(bf16x8*)(q_n + (long)row * QR + t * 8) = o;
  } else {
    int tt = t - 192;
    bf16x8 rv = *(const bf16x8*)&rope_s[(tt & 7) * 8];
    long base0 = ((long)(b * NH + (tt >> 3)) * S_ + s) * DQK + 128 + (tt & 7) * 8;
    long base1 = ((long)(b * NH + 8 + (tt >> 3)) * S_ + s) * DQK + 128 + (tt & 7) * 8;
    *(bf16x8*)(k_bhsd + base0) = rv;
    *(bf16x8*)(k_bhsd + base1) = rv;
  }
}

// ---------------- V transpose: v_rows [NTOK][2048] -> v_t [BH][128][S] --------
__global__ __launch_bounds__(256) void v_trans(const bf16* __restrict__ v_rows,
                                               bf16* __restrict__ v_t) {
  __shared__ bf16 tile[32][33];
  int st = blockIdx.x, dt = blockIdx.y, bh = blockIdx.z;
  int b = bh >> 4, h = bh & 15;
  int tx = threadIdx.x & 31, ty = threadIdx.x >> 5;
#pragma unroll
  for (int i = 0; i < 4; ++i) {
    int s = st * 32 + ty + i * 8, d = dt * 32 + tx;
    tile[ty + i * 8][tx] = v_rows[((long)(b * S_ + s)) * 2048 + h * 128 + d];
  }
  __syncthreads();
#pragma unroll
  for (int i = 0; i < 4; ++i) {
    int d = dt * 32 + ty + i * 8, s = st * 32 + tx;
    v_t[((long)bh * DV + d) * S_ + s] = tile[tx][ty + i * 8];
  }
}

// ---------------- flash v2b: ones-row PV computes l; exp2 softmax -------------
// scores arrive in log2-domain (q pre-scaled by SCALE*LOG2E). Vs has 16 extra
// rows: row 128 = 1.0 (ones), 129..143 = 0; PV dn=8 accumulates l = P @ ones
// inside oacc[8] (rescaled with the rest). No per-tile sum reduction.
#define QBLK 64
#define KVB  64
#define DVP  144
__global__ __launch_bounds__(256) void flash2(const bf16* __restrict__ q_bhsd,
                                              const bf16* __restrict__ k_bhsd,
                                              const bf16* __restrict__ v_t,
                                              bf16* __restrict__ att) {  // [NTOK][2048]
  __shared__ bf16 Ks[KVB * DQK];      // 24 KB, swizzled 16B chunks
  __shared__ bf16 Vs[DVP * KVB];      // 18 KB, rows 0-127 staged, 128-143 const
  __shared__ bf16 Ps[4][16 * 72];     // 9 KB, per-wave P, padded to 72
  int bid = blockIdx.x;
  int bh = bid & 31;                  // head-of-batch: fixes XCD = bh%8
  int qt = 31 - (bid >> 5);           // heaviest (most k-tiles) first
  int b = bh >> 4, h = bh & 15;
  int q0 = qt * QBLK;
  int t = threadIdx.x;
  int w = t >> 6, l = t & 63;
  int lr = l & 15, lg = l >> 4;
  int qw = q0 + w * 16;               // this wave's first q row

  const bf16* Qb = q_bhsd + (long)bh * S_ * DQK;
  const bf16* Kb = k_bhsd + (long)bh * S_ * DQK;
  const bf16* Vb = v_t + (long)bh * DV * S_;

  // init ones/zero rows of Vs (persist across tiles; staging never touches them)
  if (t < 128) {
    int rr = 128 + (t >> 3), cc = (t & 7) * 8;
    bf16 val = (bf16)((rr == 128) ? 1.0f : 0.0f);
    bf16x8 vvv = {val, val, val, val, val, val, val, val};
    *(bf16x8*)(Vs + rr * KVB + cc) = vvv;
  }

  bf16x8 qf[6];
#pragma unroll
  for (int t6 = 0; t6 < 6; ++t6)
    qf[t6] = *(const bf16x8*)(Qb + (long)(qw + lr) * DQK + t6 * 32 + lg * 8);

  f32x4 oacc[9] = {};                 // [0..7] output, [8] = l (ones-row)
  float mrow[4] = {-1e30f, -1e30f, -1e30f, -1e30f};
  const int lr7 = lr & 7;

  int nkt = qt + 1;
  for (int kt = 0; kt < nkt; ++kt) {
    int k0 = kt * KVB;
    __syncthreads();
    // stage K: 1536 chunks (6 x 256); slot s holds global chunk (r, c^(r&7))
#pragma unroll
    for (int j = 0; j < 6; ++j) {
      int s = j * 256 + t;
      int r = s / 24, c1 = s - r * 24;
      int c = c1 ^ (r & 7);
      gload16(Kb + (long)(k0 + r) * DQK + c * 8, Ks + (j * 256 + w * 64) * 8);
    }
    // stage V: 1024 chunks (4 x 256), rows 0..127 only
#pragma unroll
    for (int j = 0; j < 4; ++j) {
      int s = j * 256 + t;
      int d = s >> 3, c1 = s & 7;
      int c = c1 ^ (d & 7);
      gload16(Vb + (long)d * S_ + k0 + c * 8, Vs + (j * 256 + w * 64) * 8);
    }
    __syncthreads();
    if (k0 > qw + 15) continue;       // fully masked for this wave

    // ---- QK^T: sacc[n] = scores[q=lg*4+v][k=n*16+lr] (log2-domain) ----
    f32x4 sacc[4] = {};
#pragma unroll
    for (int n = 0; n < 4; ++n) {
      int rk = n * 16 + lr;
#pragma unroll
      for (int t6 = 0; t6 < 6; ++t6) {
        bf16x8 kf = *(const bf16x8*)(Ks + rk * DQK + (((t6 * 4 + lg) ^ lr7) << 3));
        sacc[n] = __builtin_amdgcn_mfma_f32_16x16x32_bf16(qf[t6], kf, sacc[n], 0, 0, 0);
      }
    }
    // ---- causal mask (diagonal tiles only) ----
    if (k0 + KVB - 1 > qw) {
#pragma unroll
      for (int n = 0; n < 4; ++n)
#pragma unroll
        for (int v = 0; v < 4; ++v) {
          int r = lg * 4 + v, c = n * 16 + lr;
          if (k0 + c > qw + r) sacc[n][v] = -1e30f;
        }
    }
    // ---- online softmax: max only (sum comes from the ones-row MFMA) ----
    float corr[4], p[4][4];
#pragma unroll
    for (int v = 0; v < 4; ++v) {
      float mv = fmaxf(fmaxf(sacc[0][v], sacc[1][v]), fmaxf(sacc[2][v], sacc[3][v]));
#pragma unroll
      for (int msk = 1; msk < 16; msk <<= 1) mv = fmaxf(mv, __shfl_xor(mv, msk));
      float mt = fmaxf(mrow[v], mv);
      corr[v] = EXP2F(mrow[v] - mt);
#pragma unroll
      for (int n = 0; n < 4; ++n) p[n][v] = EXP2F(sacc[n][v] - mt);
      mrow[v] = mt;
    }
#pragma unroll
    for (int dn = 0; dn < 9; ++dn)
#pragma unroll
      for (int v = 0; v < 4; ++v) oacc[dn][v] *= corr[v];
    // ---- P -> LDS (per-wave, padded) ----
#pragma unroll
    for (int v = 0; v < 4; ++v)
#pragma unroll
      for (int n = 0; n < 4; ++n)
        Ps[w][(lg * 4 + v) * 72 + n * 16 + lr] = (bf16)p[n][v];
    // ---- PV: oacc[dn] += P[16x64] @ V^T; dn=8 hits the ones-row => l ----
#pragma unroll
    for (int kc = 0; kc < 2; ++kc) {
      bf16x8 pf = *(const bf16x8*)(Ps[w] + lr * 72 + kc * 32 + lg * 8);
#pragma unroll
      for (int dn = 0; dn < 9; ++dn) {
        int d = dn * 16 + lr;
        bf16x8 vf = *(const bf16x8*)(Vs + d * KVB + (((kc * 4 + lg) ^ lr7) << 3));
        oacc[dn] = __builtin_amdgcn_mfma_f32_16x16x32_bf16(pf, vf, oacc[dn], 0, 0, 0);
      }
    }
  }
  // ---- epilogue: l lives in column d=128 (lanes lr==0); broadcast + divide ----
  float rl[4];
#pragma unroll
  for (int v = 0; v < 4; ++v) {
    float lv = __shfl(oacc[8][v], lg * 16);
    rl[v] = 1.0f / lv;
  }
#pragma unroll
  for (int dn = 0; dn < 8; ++dn)
#pragma unroll
    for (int v = 0; v < 4; ++v) {
      int r = lg * 4 + v;
      float o = oacc[dn][v] * rl[v];
      att[((long)(b * S_ + qw + r)) * 2048 + h * 128 + dn * 16 + lr] = (bf16)o;
    }
}

extern "C" void kernel_launch(void* const* d_in, const int* in_sizes, int n_in,
                              void* d_out, int out_size, void* d_ws, size_t ws_size,
                              hipStream_t stream) {
  const float* x        = (const float*)d_in[0];
  const int* pos        = (const int*)d_in[1];   // harness passes integers as int32
  const float* Wqa      = (const float*)d_in[2];
  const float* g_qa     = (const float*)d_in[3];
  const float* Wqb      = (const float*)d_in[4];
  const float* Wkva     = (const float*)d_in[5];
  const float* g_kva    = (const float*)d_in[6];
  const float* Wkvb     = (const float*)d_in[7];
  const float* Wo       = (const float*)d_in[8];
  const float* cosT     = (const float*)d_in[9];
  const float* sinT     = (const float*)d_in[10];
  float* out            = (float*)d_out;

  // ---- workspace layout ----
  size_t off = 0;
  char* wsp = (char*)d_ws;
  auto alloc = [&](size_t n) { void* p = wsp + off; off += (n + 255) & ~(size_t)255; return p; };
  bf16*  Wqa_t  = (bf16*) alloc((size_t)QR * HD * 2);      // contiguous with
  bf16*  Wkva_t = (bf16*) alloc((size_t)640 * HD * 2);     //  ... Wqa_t (concat Bt)
  bf16*  Wqb_t  = (bf16*) alloc((size_t)NQB * QR * 2);
  bf16*  Wkvb_t = (bf16*) alloc((size_t)NKVB * KVR * 2);
  bf16*  Wo_t   = (bf16*) alloc((size_t)HD * HD * 2);
  bf16*  x_bf   = (bf16*) alloc((size_t)NTOK * HD * 2);
  bf16*  q_bhsd = (bf16*) alloc((size_t)B_ * NH * S_ * DQK * 2);
  bf16*  k_bhsd = (bf16*) alloc((size_t)B_ * NH * S_ * DQK * 2);
  bf16*  v_rows = (bf16*) alloc((size_t)NTOK * 2048 * 2);
  bf16*  v_t    = (bf16*) alloc((size_t)B_ * NH * DV * S_ * 2);
  bf16*  att    = (bf16*) alloc((size_t)NTOK * 2048 * 2);
  char*  T      = (char*) alloc((size_t)33554432);         // 32 MB transient
  bf16*  xa  = (bf16*)T;                        // [NTOK][2176] = 17.8 MB
  bf16*  q_n = (bf16*)(T + 18874368);           // [NTOK][1536] = 12.6 MB
  bf16*  kv_l = (bf16*)(T + 18874368 + 12582912); // [NTOK][512] = 4.2 MB
  if (ws_size < off) return;

  cvt_bf16<<<(NTOK * HD / 4 + 255) / 256, 256, 0, stream>>>(x, x_bf, (long)NTOK * HD);
  transpose_cvt<<<dim3(QR / 32, HD / 32), 256, 0, stream>>>(Wqa, Wqa_t, HD, QR, QR);
  transpose_cvt<<<dim3(640 / 32, HD / 32), 256, 0, stream>>>(Wkva, Wkva_t, HD, 576, 640);
  transpose_cvt<<<dim3(NQB / 32, QR / 32), 256, 0, stream>>>(Wqb, Wqb_t, QR, NQB, NQB);
  transpose_cvt<<<dim3(NKVB / 32, KVR / 32), 256, 0, stream>>>(Wkvb, Wkvb_t, KVR, NKVB, NKVB);
  transpose_cvt<<<dim3(HD / 32, HD / 32), 256, 0, stream>>>(Wo, Wo_t, HD, HD, HD);
  // ---- combined first-stage GEMM: xa = x_bf @ [Wqa | Wkva] ----
  gemm_bf16<bf16><<<dim3(NQKVA / 128, NTOK / 128), 256, 0, stream>>>(x_bf, Wqa_t, xa, NTOK, NQKVA, HD);
  // ---- merged norms + rope prep ----
  norm_prep<<<NTOK, 256, 0, stream>>>(xa, g_qa, g_kva, pos, cosT, sinT, q_n, kv_l, k_bhsd);
  // ---- Q path ----
  gemm_qf<<<dim3(NQB / 128, NTOK / 128), 256, 0, stream>>>(q_n, Wqb_t, pos, cosT, sinT, q_bhsd);
  // ---- KV path ----
  gemm_kvb<<<dim3(NKVB / 128, NTOK / 128), 256, 0, stream>>>(kv_l, Wkvb_t, k_bhsd, v_rows);
  v_trans<<<dim3(S_ / 32, DV / 32, B_ * NH), 256, 0, stream>>>(v_rows, v_t);
  // ---- attention + output projection ----
  flash2<<<1024, 256, 0, stream>>>(q_bhsd, k_bhsd, v_t, att);
  gemm_bf16<float><<<dim3(HD / 128, NTOK / 128), 256, 0, stream>>>(att, Wo_t, out, NTOK, HD, HD);
}